// Round 3
// baseline (3216.013 us; speedup 1.0000x reference)
//
#include <hip/hip_runtime.h>
#include <hip/hip_bf16.h>
#include <cstdint>
#include <cstddef>

#define E_N 600000
#define NND 50000
#define L 128

typedef unsigned short u16;
typedef unsigned int u32;
typedef __attribute__((ext_vector_type(8))) short bf16x8;
typedef __attribute__((ext_vector_type(4))) float f32x4;

static __device__ __forceinline__ u16 f2bf(float f) {
  union { float f; u32 u; } c; c.f = f;
  return (u16)((c.u + 0x7fffu + ((c.u >> 16) & 1u)) >> 16);
}
static __device__ __forceinline__ u32 pk2(float a, float b) {
  return (u32)f2bf(a) | ((u32)f2bf(b) << 16);
}
static __device__ __forceinline__ float bf2f(u32 h) {
  union { u32 u; float f; } c; c.u = (h & 0xffffu) << 16; return c.f;
}
static __device__ __forceinline__ void atomAddF(float* p, float v) {
#if defined(__HIP_DEVICE_COMPILE__)
  unsafeAtomicAdd(p, v);
#else
  atomicAdd(p, v);
#endif
}
static __device__ __forceinline__ bf16x8 pack8(float4 a, float4 b) {
  union { bf16x8 v; u32 w[4]; } r;
  r.w[0] = pk2(a.x, a.y); r.w[1] = pk2(a.z, a.w);
  r.w[2] = pk2(b.x, b.y); r.w[3] = pk2(b.z, b.w);
  return r.v;
}
// BN(scale,shift)+ReLU on 8 packed bf16, repack to bf16x8
static __device__ __forceinline__ bf16x8 bnrelu8(bf16x8 raw, float4 sca, float4 scb,
                                                 float4 sha, float4 shb) {
  union { bf16x8 v; u16 h[8]; } in; in.v = raw;
  const float sc[8] = {sca.x, sca.y, sca.z, sca.w, scb.x, scb.y, scb.z, scb.w};
  const float sh[8] = {sha.x, sha.y, sha.z, sha.w, shb.x, shb.y, shb.z, shb.w};
  float f[8];
  #pragma unroll
  for (int i = 0; i < 8; ++i) f[i] = fmaxf(bf2f(in.h[i]) * sc[i] + sh[i], 0.f);
  union { bf16x8 v; u32 w[4]; } r;
  #pragma unroll
  for (int i = 0; i < 4; ++i) r.w[i] = pk2(f[2 * i], f[2 * i + 1]);
  return r.v;
}

// ================= prepass: fp32 -> bf16 convert (4-wide) =================
__global__ __launch_bounds__(256) void k_cvt4(const float* __restrict__ in,
                                              u16* __restrict__ out, int n4) {
  const int i = blockIdx.x * 256 + threadIdx.x;
  if (i < n4) {
    const float4 v = *(const float4*)(in + (size_t)i * 4);
    u32 w0 = pk2(v.x, v.y), w1 = pk2(v.z, v.w);
    uint2 o; o.x = w0; o.y = w1;
    *(uint2*)(out + (size_t)i * 4) = o;
  }
}

// ================= weight pre-transpose: W[4][K][128] -> Wt[4][128][K] bf16 =================
__global__ void k_wt(const float* __restrict__ W, u16* __restrict__ Wt, int K) {
  const int idx = blockIdx.x * 256 + threadIdx.x;
  const int total = 4 * K * 128;
  if (idx >= total) return;
  const int s = idx / (K * 128);
  const int rem = idx - s * K * 128;
  const int n = rem / K;
  const int k = rem - n * K;
  Wt[idx] = f2bf(W[(size_t)s * K * 128 + (size_t)k * 128 + n]);
}

// ================= CSR build =================
__global__ void k_hist(const int* __restrict__ dstI, int* __restrict__ cnt) {
  const int i = blockIdx.x * 256 + threadIdx.x;
  if (i < E_N) atomicAdd(&cnt[dstI[i]], 1);
}

__global__ __launch_bounds__(1024) void k_scan(const int* __restrict__ cnt, int* __restrict__ startA) {
  __shared__ int buf[1024];
  __shared__ int carry;
  const int tid = threadIdx.x;
  if (tid == 0) carry = 0;
  __syncthreads();
  for (int base = 0; base < NND; base += 1024) {
    int v = (base + tid < NND) ? cnt[base + tid] : 0;
    buf[tid] = v;
    __syncthreads();
    for (int off = 1; off < 1024; off <<= 1) {
      int t = (tid >= off) ? buf[tid - off] : 0;
      __syncthreads();
      buf[tid] += t;
      __syncthreads();
    }
    const int incl = buf[tid];
    const int c = carry;
    if (base + tid < NND) startA[base + tid] = c + incl - v;
    __syncthreads();
    if (tid == 1023) carry = c + incl;
    __syncthreads();
  }
  if (tid == 0) startA[NND] = carry;
}

__global__ void k_fill(const int* __restrict__ dstI, const int* __restrict__ startA,
                       int* __restrict__ cur, int* __restrict__ eids) {
  const int i = blockIdx.x * 256 + threadIdx.x;
  if (i < E_N) {
    const int d = dstI[i];
    const int pos = atomicAdd(&cur[d], 1);
    eids[startA[d] + pos] = i;
  }
}

// ================= aggregation: agg16[n] = bf16( sum of ea16 rows of in-edges ) =================
__global__ __launch_bounds__(256) void k_agg(const u16* __restrict__ ea16,
                                             const int* __restrict__ startA,
                                             const int* __restrict__ eids,
                                             u16* __restrict__ agg16) {
  const int node = blockIdx.x * 4 + (threadIdx.x >> 6);
  const int lane = threadIdx.x & 63;
  if (node >= NND) return;
  const int s = startA[node], e = startA[node + 1];
  float a0 = 0.f, a1 = 0.f, b0 = 0.f, b1 = 0.f;
  int i = s;
  for (; i + 1 < e; i += 2) {
    const u32 v0 = *(const u32*)(ea16 + (size_t)eids[i] * L + lane * 2);
    const u32 v1 = *(const u32*)(ea16 + (size_t)eids[i + 1] * L + lane * 2);
    a0 += bf2f(v0); a1 += bf2f(v0 >> 16);
    b0 += bf2f(v1); b1 += bf2f(v1 >> 16);
  }
  if (i < e) {
    const u32 v = *(const u32*)(ea16 + (size_t)eids[i] * L + lane * 2);
    a0 += bf2f(v); a1 += bf2f(v >> 16);
  }
  *(u32*)(agg16 + (size_t)node * L + lane * 2) = pk2(a0 + b0, a1 + b1);
}

// ================= BN finalize =================
__global__ void k_bnfin(const float* __restrict__ gS, const float* __restrict__ g,
                        const float* __restrict__ be, float invM, float* __restrict__ ss) {
  const int c = threadIdx.x;
  float s1 = 0.f, s2 = 0.f;
  for (int j = 0; j < 64; ++j) { s1 += gS[j * L + c]; s2 += gS[64 * L + j * L + c]; }
  const float mean = s1 * invM;
  const float var = s2 * invM - mean * mean;
  const float sc = g[c] * rsqrtf(var + 1e-5f);
  ss[c] = sc;
  ss[L + c] = be[c] - mean * sc;
}

#define MFMA(a, bfr, c) __builtin_amdgcn_mfma_f32_16x16x32_bf16((a), (bfr), (c), 0, 0, 0)

// ================= edge layer 1 (reg-direct MFMA): h1 = concat(x[dst],x[src],ea) @ W1 + b1 ; BN stats =================
template <bool EA32>
__global__ __launch_bounds__(256) void k_edge_l1(
    const u16* __restrict__ x16, const float* __restrict__ ea32,
    const u16* __restrict__ ea16,
    const int* __restrict__ srcI, const int* __restrict__ dstI,
    const u16* __restrict__ Wt, const float* __restrict__ b,
    u16* __restrict__ h1, float* __restrict__ gS)
{
  __shared__ float red[256];
  const int tid = threadIdx.x, bid = blockIdx.x, row0 = bid * 64;
  red[tid] = 0.f;
  const int lane = tid & 63, wid = tid >> 6, wr = wid >> 1, wc = wid & 1;
  const int l15 = lane & 15, lq = lane >> 4;
  const int koff = lq * 8;
  const int r0 = row0 + wr * 32 + l15, r1 = r0 + 16;
  const int d0 = dstI[r0], d1 = dstI[r1];
  const int sv0 = srcI[r0], sv1 = srcI[r1];

  const u16* Bp[4];
  #pragma unroll
  for (int n = 0; n < 4; ++n)
    Bp[n] = Wt + (size_t)(wc * 64 + n * 16 + l15) * 384 + koff;

  f32x4 acc[2][4];
  #pragma unroll
  for (int m = 0; m < 2; ++m)
    #pragma unroll
    for (int n = 0; n < 4; ++n) acc[m][n] = (f32x4){0.f, 0.f, 0.f, 0.f};

  // seg 0: x[dst], seg 1: x[src]  (bf16 shadow)
  #pragma unroll
  for (int seg = 0; seg < 2; ++seg) {
    const u16* a0 = x16 + (size_t)(seg ? sv0 : d0) * L + koff;
    const u16* a1 = x16 + (size_t)(seg ? sv1 : d1) * L + koff;
    #pragma unroll
    for (int kk = 0; kk < 4; ++kk) {
      const bf16x8 af0 = *(const bf16x8*)(a0 + kk * 32);
      const bf16x8 af1 = *(const bf16x8*)(a1 + kk * 32);
      #pragma unroll
      for (int n = 0; n < 4; ++n) {
        const bf16x8 bfr = *(const bf16x8*)(Bp[n] + seg * 128 + kk * 32);
        acc[0][n] = MFMA(af0, bfr, acc[0][n]);
        acc[1][n] = MFMA(af1, bfr, acc[1][n]);
      }
    }
  }
  // seg 2: edge_attr
  if (EA32) {
    const float* e0 = ea32 + (size_t)r0 * L + koff;
    const float* e1 = ea32 + (size_t)r1 * L + koff;
    #pragma unroll
    for (int kk = 0; kk < 4; ++kk) {
      const bf16x8 af0 = pack8(*(const float4*)(e0 + kk * 32), *(const float4*)(e0 + kk * 32 + 4));
      const bf16x8 af1 = pack8(*(const float4*)(e1 + kk * 32), *(const float4*)(e1 + kk * 32 + 4));
      #pragma unroll
      for (int n = 0; n < 4; ++n) {
        const bf16x8 bfr = *(const bf16x8*)(Bp[n] + 256 + kk * 32);
        acc[0][n] = MFMA(af0, bfr, acc[0][n]);
        acc[1][n] = MFMA(af1, bfr, acc[1][n]);
      }
    }
  } else {
    const u16* e0 = ea16 + (size_t)r0 * L + koff;
    const u16* e1 = ea16 + (size_t)r1 * L + koff;
    #pragma unroll
    for (int kk = 0; kk < 4; ++kk) {
      const bf16x8 af0 = *(const bf16x8*)(e0 + kk * 32);
      const bf16x8 af1 = *(const bf16x8*)(e1 + kk * 32);
      #pragma unroll
      for (int n = 0; n < 4; ++n) {
        const bf16x8 bfr = *(const bf16x8*)(Bp[n] + 256 + kk * 32);
        acc[0][n] = MFMA(af0, bfr, acc[0][n]);
        acc[1][n] = MFMA(af1, bfr, acc[1][n]);
      }
    }
  }

  float bb[4], s1[4], s2[4];
  #pragma unroll
  for (int n = 0; n < 4; ++n) { bb[n] = b[wc * 64 + n * 16 + l15]; s1[n] = 0.f; s2[n] = 0.f; }
  #pragma unroll
  for (int m = 0; m < 2; ++m)
    #pragma unroll
    for (int n = 0; n < 4; ++n) {
      const int col = wc * 64 + n * 16 + l15;
      #pragma unroll
      for (int r = 0; r < 4; ++r) {
        const int row = row0 + wr * 32 + m * 16 + lq * 4 + r;
        const float o = acc[m][n][r] + bb[n];
        s1[n] += o; s2[n] += o * o;
        h1[(size_t)row * L + col] = f2bf(o);
      }
    }
  __syncthreads();
  #pragma unroll
  for (int n = 0; n < 4; ++n) {
    const int col = wc * 64 + n * 16 + l15;
    atomAddF(&red[col], s1[n]);
    atomAddF(&red[128 + col], s2[n]);
  }
  __syncthreads();
  const int slot = (bid & 63) * L;
  if (tid < 128) atomAddF(&gS[slot + tid], red[tid]);
  else atomAddF(&gS[64 * L + slot + (tid - 128)], red[tid]);
}

// ================= edge layer 2 (reg-direct MFMA): ea = relu(relu(BN(h1)) @ W2 + b2) + resid ; bf16 shadow =================
__global__ __launch_bounds__(256) void k_edge_l2(
    const u16* __restrict__ h1, const float* __restrict__ ss,
    const u16* __restrict__ Wt, const float* __restrict__ b,
    const float* __restrict__ resid, float* __restrict__ ea_out,
    u16* __restrict__ ea16)
{
  const int tid = threadIdx.x, bid = blockIdx.x, row0 = bid * 64;
  const int lane = tid & 63, wid = tid >> 6, wr = wid >> 1, wc = wid & 1;
  const int l15 = lane & 15, lq = lane >> 4;
  const int koff = lq * 8;
  const int r0 = row0 + wr * 32 + l15, r1 = r0 + 16;
  const u16* a0 = h1 + (size_t)r0 * L + koff;
  const u16* a1 = h1 + (size_t)r1 * L + koff;
  const u16* Bp[4];
  #pragma unroll
  for (int n = 0; n < 4; ++n)
    Bp[n] = Wt + (size_t)(wc * 64 + n * 16 + l15) * 128 + koff;

  f32x4 acc[2][4];
  #pragma unroll
  for (int m = 0; m < 2; ++m)
    #pragma unroll
    for (int n = 0; n < 4; ++n) acc[m][n] = (f32x4){0.f, 0.f, 0.f, 0.f};

  #pragma unroll
  for (int kk = 0; kk < 4; ++kk) {
    const float* scp = ss + kk * 32 + koff;
    const float* shp = ss + 128 + kk * 32 + koff;
    const float4 sca = *(const float4*)scp, scb = *(const float4*)(scp + 4);
    const float4 sha = *(const float4*)shp, shb = *(const float4*)(shp + 4);
    const bf16x8 af0 = bnrelu8(*(const bf16x8*)(a0 + kk * 32), sca, scb, sha, shb);
    const bf16x8 af1 = bnrelu8(*(const bf16x8*)(a1 + kk * 32), sca, scb, sha, shb);
    #pragma unroll
    for (int n = 0; n < 4; ++n) {
      const bf16x8 bfr = *(const bf16x8*)(Bp[n] + kk * 32);
      acc[0][n] = MFMA(af0, bfr, acc[0][n]);
      acc[1][n] = MFMA(af1, bfr, acc[1][n]);
    }
  }

  float bb[4];
  #pragma unroll
  for (int n = 0; n < 4; ++n) bb[n] = b[wc * 64 + n * 16 + l15];
  #pragma unroll
  for (int m = 0; m < 2; ++m)
    #pragma unroll
    for (int n = 0; n < 4; ++n) {
      const int col = wc * 64 + n * 16 + l15;
      #pragma unroll
      for (int r = 0; r < 4; ++r) {
        const int row = row0 + wr * 32 + m * 16 + lq * 4 + r;
        const float o = fmaxf(acc[m][n][r] + bb[n], 0.f) + resid[(size_t)row * L + col];
        ea_out[(size_t)row * L + col] = o;
        ea16[(size_t)row * L + col] = f2bf(o);
      }
    }
}

// ================= node layer 1 (reg-direct MFMA): h1n = concat(x,agg) @ nW1 + nb1 ; BN stats =================
__global__ __launch_bounds__(256) void k_node_l1(
    const u16* __restrict__ x16, const u16* __restrict__ agg16,
    const u16* __restrict__ Wt, const float* __restrict__ b,
    u16* __restrict__ h1, float* __restrict__ gS)
{
  __shared__ float red[256];
  const int tid = threadIdx.x, bid = blockIdx.x, row0 = bid * 64;
  red[tid] = 0.f;
  const int lane = tid & 63, wid = tid >> 6, wr = wid >> 1, wc = wid & 1;
  const int l15 = lane & 15, lq = lane >> 4;
  const int koff = lq * 8;
  const int r0 = row0 + wr * 32 + l15, r1 = r0 + 16;
  const int rr0 = min(r0, NND - 1), rr1 = min(r1, NND - 1);

  const u16* Bp[4];
  #pragma unroll
  for (int n = 0; n < 4; ++n)
    Bp[n] = Wt + (size_t)(wc * 64 + n * 16 + l15) * 256 + koff;

  f32x4 acc[2][4];
  #pragma unroll
  for (int m = 0; m < 2; ++m)
    #pragma unroll
    for (int n = 0; n < 4; ++n) acc[m][n] = (f32x4){0.f, 0.f, 0.f, 0.f};

  #pragma unroll
  for (int seg = 0; seg < 2; ++seg) {
    const u16* base = seg ? agg16 : x16;
    const u16* a0 = base + (size_t)rr0 * L + koff;
    const u16* a1 = base + (size_t)rr1 * L + koff;
    #pragma unroll
    for (int kk = 0; kk < 4; ++kk) {
      const bf16x8 af0 = *(const bf16x8*)(a0 + kk * 32);
      const bf16x8 af1 = *(const bf16x8*)(a1 + kk * 32);
      #pragma unroll
      for (int n = 0; n < 4; ++n) {
        const bf16x8 bfr = *(const bf16x8*)(Bp[n] + seg * 128 + kk * 32);
        acc[0][n] = MFMA(af0, bfr, acc[0][n]);
        acc[1][n] = MFMA(af1, bfr, acc[1][n]);
      }
    }
  }

  float bb[4], s1[4], s2[4];
  #pragma unroll
  for (int n = 0; n < 4; ++n) { bb[n] = b[wc * 64 + n * 16 + l15]; s1[n] = 0.f; s2[n] = 0.f; }
  #pragma unroll
  for (int m = 0; m < 2; ++m)
    #pragma unroll
    for (int n = 0; n < 4; ++n) {
      const int col = wc * 64 + n * 16 + l15;
      #pragma unroll
      for (int r = 0; r < 4; ++r) {
        const int row = row0 + wr * 32 + m * 16 + lq * 4 + r;
        if (row < NND) {
          const float o = acc[m][n][r] + bb[n];
          s1[n] += o; s2[n] += o * o;
          h1[(size_t)row * L + col] = f2bf(o);
        }
      }
    }
  __syncthreads();
  #pragma unroll
  for (int n = 0; n < 4; ++n) {
    const int col = wc * 64 + n * 16 + l15;
    atomAddF(&red[col], s1[n]);
    atomAddF(&red[128 + col], s2[n]);
  }
  __syncthreads();
  const int slot = (bid & 63) * L;
  if (tid < 128) atomAddF(&gS[slot + tid], red[tid]);
  else atomAddF(&gS[64 * L + slot + (tid - 128)], red[tid]);
}

// ================= node layer 2 (reg-direct MFMA): x = relu(relu(BN(h1n)) @ nW2 + nb2) + resid ; bf16 shadow =================
__global__ __launch_bounds__(256) void k_node_l2(
    const u16* __restrict__ h1, const float* __restrict__ ss,
    const u16* __restrict__ Wt, const float* __restrict__ b,
    const float* __restrict__ resid, float* __restrict__ x_out,
    u16* __restrict__ x16)
{
  const int tid = threadIdx.x, bid = blockIdx.x, row0 = bid * 64;
  const int lane = tid & 63, wid = tid >> 6, wr = wid >> 1, wc = wid & 1;
  const int l15 = lane & 15, lq = lane >> 4;
  const int koff = lq * 8;
  const int r0 = row0 + wr * 32 + l15, r1 = r0 + 16;
  const int rr0 = min(r0, NND - 1), rr1 = min(r1, NND - 1);
  const u16* a0 = h1 + (size_t)rr0 * L + koff;
  const u16* a1 = h1 + (size_t)rr1 * L + koff;
  const u16* Bp[4];
  #pragma unroll
  for (int n = 0; n < 4; ++n)
    Bp[n] = Wt + (size_t)(wc * 64 + n * 16 + l15) * 128 + koff;

  f32x4 acc[2][4];
  #pragma unroll
  for (int m = 0; m < 2; ++m)
    #pragma unroll
    for (int n = 0; n < 4; ++n) acc[m][n] = (f32x4){0.f, 0.f, 0.f, 0.f};

  #pragma unroll
  for (int kk = 0; kk < 4; ++kk) {
    const float* scp = ss + kk * 32 + koff;
    const float* shp = ss + 128 + kk * 32 + koff;
    const float4 sca = *(const float4*)scp, scb = *(const float4*)(scp + 4);
    const float4 sha = *(const float4*)shp, shb = *(const float4*)(shp + 4);
    const bf16x8 af0 = bnrelu8(*(const bf16x8*)(a0 + kk * 32), sca, scb, sha, shb);
    const bf16x8 af1 = bnrelu8(*(const bf16x8*)(a1 + kk * 32), sca, scb, sha, shb);
    #pragma unroll
    for (int n = 0; n < 4; ++n) {
      const bf16x8 bfr = *(const bf16x8*)(Bp[n] + kk * 32);
      acc[0][n] = MFMA(af0, bfr, acc[0][n]);
      acc[1][n] = MFMA(af1, bfr, acc[1][n]);
    }
  }

  float bb[4];
  #pragma unroll
  for (int n = 0; n < 4; ++n) bb[n] = b[wc * 64 + n * 16 + l15];
  #pragma unroll
  for (int m = 0; m < 2; ++m)
    #pragma unroll
    for (int n = 0; n < 4; ++n) {
      const int col = wc * 64 + n * 16 + l15;
      #pragma unroll
      for (int r = 0; r < 4; ++r) {
        const int row = row0 + wr * 32 + m * 16 + lq * 4 + r;
        if (row < NND) {
          const float o = fmaxf(acc[m][n][r] + bb[n], 0.f) + resid[(size_t)row * L + col];
          x_out[(size_t)row * L + col] = o;
          x16[(size_t)row * L + col] = f2bf(o);
        }
      }
    }
}

extern "C" void kernel_launch(void* const* d_in, const int* in_sizes, int n_in,
                              void* d_out, int out_size, void* d_ws, size_t ws_size,
                              hipStream_t stream) {
  (void)in_sizes; (void)n_in; (void)out_size; (void)ws_size;
  const float* in_x  = (const float*)d_in[0];
  const float* in_ea = (const float*)d_in[1];
  const int*   ei    = (const int*)d_in[2];
  const float* eW1 = (const float*)d_in[3];
  const float* eb1 = (const float*)d_in[4];
  const float* eg1 = (const float*)d_in[5];
  const float* ebe1= (const float*)d_in[6];
  const float* eW2 = (const float*)d_in[7];
  const float* eb2 = (const float*)d_in[8];
  const float* nW1 = (const float*)d_in[9];
  const float* nb1 = (const float*)d_in[10];
  const float* ng1 = (const float*)d_in[11];
  const float* nbe1= (const float*)d_in[12];
  const float* nW2 = (const float*)d_in[13];
  const float* nb2 = (const float*)d_in[14];

  float* x  = (float*)d_out;                    // [NND][L]
  float* ea = (float*)d_out + (size_t)NND * L;  // [E_N][L]

  char* w = (char*)d_ws;
  u16* h1e  = (u16*)w;   w += (size_t)E_N * L * sizeof(u16);   // 153.6 MB
  u16* ea16 = (u16*)w;   w += (size_t)E_N * L * sizeof(u16);   // 153.6 MB
  u16* h1n  = (u16*)w;   w += (size_t)NND * L * sizeof(u16);   // 12.8 MB
  u16* x16  = (u16*)w;   w += (size_t)NND * L * sizeof(u16);   // 12.8 MB
  u16* agg16= (u16*)w;   w += (size_t)NND * L * sizeof(u16);   // 12.8 MB
  float* gS  = (float*)w; w += (size_t)2 * 64 * L * sizeof(float);
  float* ss  = (float*)w; w += 4096;
  u16* eW1t = (u16*)w;   w += (size_t)4 * 128 * 384 * sizeof(u16);
  u16* eW2t = (u16*)w;   w += (size_t)4 * 128 * 128 * sizeof(u16);
  u16* nW1t = (u16*)w;   w += (size_t)4 * 128 * 256 * sizeof(u16);
  u16* nW2t = (u16*)w;   w += (size_t)4 * 128 * 128 * sizeof(u16);
  int* cnt    = (int*)w; w += (size_t)NND * sizeof(int);
  int* cur    = (int*)w; w += (size_t)NND * sizeof(int);
  int* startA = (int*)w; w += (size_t)(NND + 1) * sizeof(int);
  int* eids   = (int*)w; w += (size_t)E_N * sizeof(int);

  const int* srcI = ei;        // edge_index[0]
  const int* dstI = ei + E_N;  // edge_index[1]

  // ---- per-launch pre-pass: x bf16 shadow + weight transpose + CSR build ----
  k_cvt4<<<(NND * L / 4 + 255) / 256, 256, 0, stream>>>(in_x, x16, NND * L / 4);
  k_wt<<<(4 * 384 * 128 + 255) / 256, 256, 0, stream>>>(eW1, eW1t, 384);
  k_wt<<<(4 * 128 * 128 + 255) / 256, 256, 0, stream>>>(eW2, eW2t, 128);
  k_wt<<<(4 * 256 * 128 + 255) / 256, 256, 0, stream>>>(nW1, nW1t, 256);
  k_wt<<<(4 * 128 * 128 + 255) / 256, 256, 0, stream>>>(nW2, nW2t, 128);
  hipMemsetAsync(cnt, 0, (size_t)NND * sizeof(int), stream);
  hipMemsetAsync(cur, 0, (size_t)NND * sizeof(int), stream);
  k_hist<<<(E_N + 255) / 256, 256, 0, stream>>>(dstI, cnt);
  k_scan<<<1, 1024, 0, stream>>>(cnt, startA);
  k_fill<<<(E_N + 255) / 256, 256, 0, stream>>>(dstI, startA, cur, eids);

  const int egrid = E_N / 64;            // 9375
  const int ngrid = (NND + 63) / 64;     // 782

  for (int s = 0; s < 4; ++s) {
    hipMemsetAsync(gS, 0, (size_t)2 * 64 * L * sizeof(float), stream);
    if (s == 0)
      k_edge_l1<true><<<egrid, 256, 0, stream>>>(x16, in_ea, nullptr, srcI, dstI,
          eW1t + (size_t)s * 128 * 384, eb1 + (size_t)s * L, h1e, gS);
    else
      k_edge_l1<false><<<egrid, 256, 0, stream>>>(x16, nullptr, ea16, srcI, dstI,
          eW1t + (size_t)s * 128 * 384, eb1 + (size_t)s * L, h1e, gS);
    k_bnfin<<<1, 128, 0, stream>>>(gS, eg1 + (size_t)s * L, ebe1 + (size_t)s * L,
        1.f / (float)E_N, ss);
    k_edge_l2<<<egrid, 256, 0, stream>>>(h1e, ss,
        eW2t + (size_t)s * 128 * 128, eb2 + (size_t)s * L,
        (s == 0) ? in_ea : ea, ea, ea16);
    k_agg<<<(NND + 3) / 4, 256, 0, stream>>>(ea16, startA, eids, agg16);
    hipMemsetAsync(gS, 0, (size_t)2 * 64 * L * sizeof(float), stream);
    k_node_l1<<<ngrid, 256, 0, stream>>>(x16, agg16,
        nW1t + (size_t)s * 128 * 256, nb1 + (size_t)s * L, h1n, gS);
    k_bnfin<<<1, 128, 0, stream>>>(gS, ng1 + (size_t)s * L, nbe1 + (size_t)s * L,
        1.f / (float)NND, ss);
    k_node_l2<<<ngrid, 256, 0, stream>>>(h1n, ss,
        nW2t + (size_t)s * 128 * 128, nb2 + (size_t)s * L,
        (s == 0) ? in_x : x, x, x16);
  }
}

// Round 4
// 2300.337 us; speedup vs baseline: 1.3981x; 1.3981x over previous
//
#include <hip/hip_runtime.h>
#include <hip/hip_bf16.h>
#include <cstdint>
#include <cstddef>

#define E_N 600000
#define NND 50000
#define L 128

typedef unsigned short u16;
typedef unsigned int u32;
typedef __attribute__((ext_vector_type(8))) short bf16x8;
typedef __attribute__((ext_vector_type(4))) float f32x4;

static __device__ __forceinline__ u16 f2bf(float f) {
  union { float f; u32 u; } c; c.f = f;
  return (u16)((c.u + 0x7fffu + ((c.u >> 16) & 1u)) >> 16);
}
static __device__ __forceinline__ u32 pk2(float a, float b) {
  return (u32)f2bf(a) | ((u32)f2bf(b) << 16);
}
static __device__ __forceinline__ float bf2f(u32 h) {
  union { u32 u; float f; } c; c.u = (h & 0xffffu) << 16; return c.f;
}
static __device__ __forceinline__ void atomAddF(float* p, float v) {
#if defined(__HIP_DEVICE_COMPILE__)
  unsafeAtomicAdd(p, v);
#else
  atomicAdd(p, v);
#endif
}
static __device__ __forceinline__ bf16x8 pack8(float4 a, float4 b) {
  union { bf16x8 v; u32 w[4]; } r;
  r.w[0] = pk2(a.x, a.y); r.w[1] = pk2(a.z, a.w);
  r.w[2] = pk2(b.x, b.y); r.w[3] = pk2(b.z, b.w);
  return r.v;
}
// BN(scale,shift)+ReLU on 8 packed bf16, repack to bf16x8
static __device__ __forceinline__ bf16x8 bnrelu8(bf16x8 raw, float4 sca, float4 scb,
                                                 float4 sha, float4 shb) {
  union { bf16x8 v; u16 h[8]; } in; in.v = raw;
  const float sc[8] = {sca.x, sca.y, sca.z, sca.w, scb.x, scb.y, scb.z, scb.w};
  const float sh[8] = {sha.x, sha.y, sha.z, sha.w, shb.x, shb.y, shb.z, shb.w};
  float f[8];
  #pragma unroll
  for (int i = 0; i < 8; ++i) f[i] = fmaxf(bf2f(in.h[i]) * sc[i] + sh[i], 0.f);
  union { bf16x8 v; u32 w[4]; } r;
  #pragma unroll
  for (int i = 0; i < 4; ++i) r.w[i] = pk2(f[2 * i], f[2 * i + 1]);
  return r.v;
}

#define MFMA(a, bfr, c) __builtin_amdgcn_mfma_f32_16x16x32_bf16((a), (bfr), (c), 0, 0, 0)

// ---- B-chunk staging: Wt rows n=0..127, k-window [kc*64, kc*64+64), 16 KB, XOR-swizzled ----
struct Stg { uint4 v[4]; };
template <int KF>
static __device__ __forceinline__ void stageLoad(const u16* __restrict__ Wt, int kc, int tid, Stg& s) {
  #pragma unroll
  for (int i = 0; i < 4; ++i) {
    const int slot = tid + i * 256;
    const int n = slot >> 3, kq = slot & 7;
    s.v[i] = *(const uint4*)(Wt + (size_t)n * KF + kc * 64 + kq * 8);
  }
}
static __device__ __forceinline__ void stageWrite(char* BsB, int tid, const Stg& s) {
  #pragma unroll
  for (int i = 0; i < 4; ++i) {
    const int slot = tid + i * 256;
    const int n = slot >> 3, kq = slot & 7;
    *(uint4*)(BsB + ((n * 128 + kq * 16) ^ ((n & 7) << 4))) = s.v[i];
  }
}
// ---- one 64-k chunk of MFMA: A frags in regs, B frags from swizzled LDS ----
static __device__ __forceinline__ void chunkMFMA(const char* BsB, int wc, int l15, int lq,
                                                 const bf16x8 (&af)[2][2], f32x4 (&acc)[2][4]) {
  #pragma unroll
  for (int k2 = 0; k2 < 2; ++k2) {
    #pragma unroll
    for (int n = 0; n < 4; ++n) {
      const int col = wc * 64 + n * 16 + l15;
      const bf16x8 bfr = *(const bf16x8*)(BsB + ((col * 128 + k2 * 64 + lq * 16) ^ ((col & 7) << 4)));
      acc[0][n] = MFMA(af[0][k2], bfr, acc[0][n]);
      acc[1][n] = MFMA(af[1][k2], bfr, acc[1][n]);
    }
  }
}

// ================= prepass: fp32 -> bf16 convert (4-wide) =================
__global__ __launch_bounds__(256) void k_cvt4(const float* __restrict__ in,
                                              u16* __restrict__ out, int n4) {
  const int i = blockIdx.x * 256 + threadIdx.x;
  if (i < n4) {
    const float4 v = *(const float4*)(in + (size_t)i * 4);
    uint2 o; o.x = pk2(v.x, v.y); o.y = pk2(v.z, v.w);
    *(uint2*)(out + (size_t)i * 4) = o;
  }
}

// ================= weight pre-transpose: W[4][K][128] -> Wt[4][128][K] bf16 =================
__global__ void k_wt(const float* __restrict__ W, u16* __restrict__ Wt, int K) {
  const int idx = blockIdx.x * 256 + threadIdx.x;
  const int total = 4 * K * 128;
  if (idx >= total) return;
  const int s = idx / (K * 128);
  const int rem = idx - s * K * 128;
  const int n = rem / K;
  const int k = rem - n * K;
  Wt[idx] = f2bf(W[(size_t)s * K * 128 + (size_t)k * 128 + n]);
}

// ================= CSR build =================
__global__ void k_hist(const int* __restrict__ dstI, int* __restrict__ cnt) {
  const int i = blockIdx.x * 256 + threadIdx.x;
  if (i < E_N) atomicAdd(&cnt[dstI[i]], 1);
}

__global__ __launch_bounds__(1024) void k_scan(const int* __restrict__ cnt, int* __restrict__ startA) {
  __shared__ int buf[1024];
  __shared__ int carry;
  const int tid = threadIdx.x;
  if (tid == 0) carry = 0;
  __syncthreads();
  for (int base = 0; base < NND; base += 1024) {
    int v = (base + tid < NND) ? cnt[base + tid] : 0;
    buf[tid] = v;
    __syncthreads();
    for (int off = 1; off < 1024; off <<= 1) {
      int t = (tid >= off) ? buf[tid - off] : 0;
      __syncthreads();
      buf[tid] += t;
      __syncthreads();
    }
    const int incl = buf[tid];
    const int c = carry;
    if (base + tid < NND) startA[base + tid] = c + incl - v;
    __syncthreads();
    if (tid == 1023) carry = c + incl;
    __syncthreads();
  }
  if (tid == 0) startA[NND] = carry;
}

__global__ void k_fill(const int* __restrict__ dstI, const int* __restrict__ startA,
                       int* __restrict__ cur, int* __restrict__ eids) {
  const int i = blockIdx.x * 256 + threadIdx.x;
  if (i < E_N) {
    const int d = dstI[i];
    const int pos = atomicAdd(&cur[d], 1);
    eids[startA[d] + pos] = i;
  }
}

// ================= aggregation: agg16[n] = bf16( sum of ea16 rows of in-edges ) =================
__global__ __launch_bounds__(256) void k_agg(const u16* __restrict__ ea16,
                                             const int* __restrict__ startA,
                                             const int* __restrict__ eids,
                                             u16* __restrict__ agg16) {
  const int node = blockIdx.x * 4 + (threadIdx.x >> 6);
  const int lane = threadIdx.x & 63;
  if (node >= NND) return;
  const int s = startA[node], e = startA[node + 1];
  float a0 = 0.f, a1 = 0.f, b0 = 0.f, b1 = 0.f;
  int i = s;
  for (; i + 1 < e; i += 2) {
    const u32 v0 = *(const u32*)(ea16 + (size_t)eids[i] * L + lane * 2);
    const u32 v1 = *(const u32*)(ea16 + (size_t)eids[i + 1] * L + lane * 2);
    a0 += bf2f(v0); a1 += bf2f(v0 >> 16);
    b0 += bf2f(v1); b1 += bf2f(v1 >> 16);
  }
  if (i < e) {
    const u32 v = *(const u32*)(ea16 + (size_t)eids[i] * L + lane * 2);
    a0 += bf2f(v); a1 += bf2f(v >> 16);
  }
  *(u32*)(agg16 + (size_t)node * L + lane * 2) = pk2(a0 + b0, a1 + b1);
}

// ================= BN finalize =================
__global__ void k_bnfin(const float* __restrict__ gS, const float* __restrict__ g,
                        const float* __restrict__ be, float invM, float* __restrict__ ss) {
  const int c = threadIdx.x;
  float s1 = 0.f, s2 = 0.f;
  for (int j = 0; j < 64; ++j) { s1 += gS[j * L + c]; s2 += gS[64 * L + j * L + c]; }
  const float mean = s1 * invM;
  const float var = s2 * invM - mean * mean;
  const float sc = g[c] * rsqrtf(var + 1e-5f);
  ss[c] = sc;
  ss[L + c] = be[c] - mean * sc;
}

// ================= edge layer 1: h1 = concat(x[dst],x[src],ea) @ W1 + b1 ; BN stats =================
template <bool EA32>
__global__ __launch_bounds__(256) void k_edge_l1(
    const u16* __restrict__ x16, const float* __restrict__ ea32,
    const u16* __restrict__ ea16,
    const int* __restrict__ srcI, const int* __restrict__ dstI,
    const u16* __restrict__ Wt, const float* __restrict__ b,
    u16* __restrict__ h1, float* __restrict__ gS)
{
  __shared__ char Bs[2][16384];
  __shared__ float red[256];
  const int tid = threadIdx.x, bid = blockIdx.x, row0 = bid * 64;
  red[tid] = 0.f;
  const int lane = tid & 63, wid = tid >> 6, wr = wid >> 1, wc = wid & 1;
  const int l15 = lane & 15, lq = lane >> 4;
  const int r0 = row0 + wr * 32 + l15, r1 = r0 + 16;
  const int d0 = dstI[r0], d1 = dstI[r1];
  const int sv0 = srcI[r0], sv1 = srcI[r1];

  const u16* aP[2][3];
  aP[0][0] = x16 + (size_t)d0 * L;  aP[1][0] = x16 + (size_t)d1 * L;
  aP[0][1] = x16 + (size_t)sv0 * L; aP[1][1] = x16 + (size_t)sv1 * L;
  if (!EA32) { aP[0][2] = ea16 + (size_t)r0 * L; aP[1][2] = ea16 + (size_t)r1 * L; }
  const float* eP0 = ea32 + (size_t)r0 * L;
  const float* eP1 = ea32 + (size_t)r1 * L;

  f32x4 acc[2][4];
  #pragma unroll
  for (int m = 0; m < 2; ++m)
    #pragma unroll
    for (int n = 0; n < 4; ++n) acc[m][n] = (f32x4){0.f, 0.f, 0.f, 0.f};

  auto loadA = [&](int c, bf16x8 (&af)[2][2]) {
    const int seg = c >> 1;
    const int base = (c & 1) * 64 + lq * 8;
    if (EA32 && seg == 2) {
      #pragma unroll
      for (int k2 = 0; k2 < 2; ++k2) {
        af[0][k2] = pack8(*(const float4*)(eP0 + base + k2 * 32),
                          *(const float4*)(eP0 + base + k2 * 32 + 4));
        af[1][k2] = pack8(*(const float4*)(eP1 + base + k2 * 32),
                          *(const float4*)(eP1 + base + k2 * 32 + 4));
      }
    } else {
      #pragma unroll
      for (int k2 = 0; k2 < 2; ++k2) {
        af[0][k2] = *(const bf16x8*)(aP[0][seg] + base + k2 * 32);
        af[1][k2] = *(const bf16x8*)(aP[1][seg] + base + k2 * 32);
      }
    }
  };

  bf16x8 aCur[2][2], aNxt[2][2];
  Stg sg;
  loadA(0, aCur);
  stageLoad<384>(Wt, 0, tid, sg);
  stageWrite(Bs[0], tid, sg);
  __syncthreads();
  #pragma unroll
  for (int c = 0; c < 6; ++c) {
    if (c + 1 < 6) { loadA(c + 1, aNxt); stageLoad<384>(Wt, c + 1, tid, sg); }
    chunkMFMA(Bs[c & 1], wc, l15, lq, aCur, acc);
    if (c + 1 < 6) stageWrite(Bs[(c + 1) & 1], tid, sg);
    __syncthreads();
    #pragma unroll
    for (int m = 0; m < 2; ++m)
      #pragma unroll
      for (int k2 = 0; k2 < 2; ++k2) aCur[m][k2] = aNxt[m][k2];
  }

  float bb[4], s1[4], s2[4];
  #pragma unroll
  for (int n = 0; n < 4; ++n) { bb[n] = b[wc * 64 + n * 16 + l15]; s1[n] = 0.f; s2[n] = 0.f; }
  #pragma unroll
  for (int m = 0; m < 2; ++m)
    #pragma unroll
    for (int n = 0; n < 4; ++n) {
      const int col = wc * 64 + n * 16 + l15;
      #pragma unroll
      for (int r = 0; r < 4; ++r) {
        const int row = row0 + wr * 32 + m * 16 + lq * 4 + r;
        const float o = acc[m][n][r] + bb[n];
        s1[n] += o; s2[n] += o * o;
        h1[(size_t)row * L + col] = f2bf(o);
      }
    }
  #pragma unroll
  for (int n = 0; n < 4; ++n) {
    const int col = wc * 64 + n * 16 + l15;
    atomAddF(&red[col], s1[n]);
    atomAddF(&red[128 + col], s2[n]);
  }
  __syncthreads();
  const int slot = (bid & 63) * L;
  if (tid < 128) atomAddF(&gS[slot + tid], red[tid]);
  else atomAddF(&gS[64 * L + slot + (tid - 128)], red[tid]);
}

// ================= edge layer 2: ea16 = bf16( relu(relu(BN(h1)) @ W2 + b2) + resid ) =================
template <bool EA32, bool WF32>
__global__ __launch_bounds__(256) void k_edge_l2(
    const u16* __restrict__ h1, const float* __restrict__ ss,
    const u16* __restrict__ Wt, const float* __restrict__ b,
    const float* __restrict__ resid32, const u16* __restrict__ resid16,
    float* __restrict__ ea_out, u16* __restrict__ ea16)
{
  __shared__ char Bs[2][16384];
  const int tid = threadIdx.x, bid = blockIdx.x, row0 = bid * 64;
  const int lane = tid & 63, wid = tid >> 6, wr = wid >> 1, wc = wid & 1;
  const int l15 = lane & 15, lq = lane >> 4;
  const int r0 = row0 + wr * 32 + l15, r1 = r0 + 16;
  const u16* a0 = h1 + (size_t)r0 * L + lq * 8;
  const u16* a1 = h1 + (size_t)r1 * L + lq * 8;

  f32x4 acc[2][4];
  #pragma unroll
  for (int m = 0; m < 2; ++m)
    #pragma unroll
    for (int n = 0; n < 4; ++n) acc[m][n] = (f32x4){0.f, 0.f, 0.f, 0.f};

  // stage both 64-k chunks of B (full K=128) up front; single barrier
  Stg sg0, sg1;
  stageLoad<128>(Wt, 0, tid, sg0);
  stageLoad<128>(Wt, 1, tid, sg1);
  // prefetch raw A frags for both chunks
  bf16x8 raw[2][2][2]; // [chunk][m][k2]
  #pragma unroll
  for (int c = 0; c < 2; ++c)
    #pragma unroll
    for (int k2 = 0; k2 < 2; ++k2) {
      raw[c][0][k2] = *(const bf16x8*)(a0 + c * 64 + k2 * 32);
      raw[c][1][k2] = *(const bf16x8*)(a1 + c * 64 + k2 * 32);
    }
  stageWrite(Bs[0], tid, sg0);
  stageWrite(Bs[1], tid, sg1);
  __syncthreads();

  #pragma unroll
  for (int c = 0; c < 2; ++c) {
    bf16x8 af[2][2];
    #pragma unroll
    for (int k2 = 0; k2 < 2; ++k2) {
      const int kg = c * 64 + k2 * 32 + lq * 8;
      const float4 sca = *(const float4*)(ss + kg), scb = *(const float4*)(ss + kg + 4);
      const float4 sha = *(const float4*)(ss + 128 + kg), shb = *(const float4*)(ss + 128 + kg + 4);
      af[0][k2] = bnrelu8(raw[c][0][k2], sca, scb, sha, shb);
      af[1][k2] = bnrelu8(raw[c][1][k2], sca, scb, sha, shb);
    }
    chunkMFMA(Bs[c], wc, l15, lq, af, acc);
  }

  float bb[4];
  #pragma unroll
  for (int n = 0; n < 4; ++n) bb[n] = b[wc * 64 + n * 16 + l15];
  #pragma unroll
  for (int m = 0; m < 2; ++m)
    #pragma unroll
    for (int n = 0; n < 4; ++n) {
      const int col = wc * 64 + n * 16 + l15;
      #pragma unroll
      for (int r = 0; r < 4; ++r) {
        const int row = row0 + wr * 32 + m * 16 + lq * 4 + r;
        const float rs = EA32 ? resid32[(size_t)row * L + col]
                              : bf2f(resid16[(size_t)row * L + col]);
        const float o = fmaxf(acc[m][n][r] + bb[n], 0.f) + rs;
        if (WF32) ea_out[(size_t)row * L + col] = o;
        ea16[(size_t)row * L + col] = f2bf(o);
      }
    }
}

// ================= node layer 1: h1n = concat(x,agg) @ nW1 + nb1 ; BN stats =================
__global__ __launch_bounds__(256) void k_node_l1(
    const u16* __restrict__ x16, const u16* __restrict__ agg16,
    const u16* __restrict__ Wt, const float* __restrict__ b,
    u16* __restrict__ h1, float* __restrict__ gS)
{
  __shared__ char Bs[2][16384];
  __shared__ float red[256];
  const int tid = threadIdx.x, bid = blockIdx.x, row0 = bid * 64;
  red[tid] = 0.f;
  const int lane = tid & 63, wid = tid >> 6, wr = wid >> 1, wc = wid & 1;
  const int l15 = lane & 15, lq = lane >> 4;
  const int r0 = row0 + wr * 32 + l15, r1 = r0 + 16;
  const int rr0 = min(r0, NND - 1), rr1 = min(r1, NND - 1);

  const u16* aP[2][2];
  aP[0][0] = x16 + (size_t)rr0 * L;  aP[1][0] = x16 + (size_t)rr1 * L;
  aP[0][1] = agg16 + (size_t)rr0 * L; aP[1][1] = agg16 + (size_t)rr1 * L;

  f32x4 acc[2][4];
  #pragma unroll
  for (int m = 0; m < 2; ++m)
    #pragma unroll
    for (int n = 0; n < 4; ++n) acc[m][n] = (f32x4){0.f, 0.f, 0.f, 0.f};

  auto loadA = [&](int c, bf16x8 (&af)[2][2]) {
    const int seg = c >> 1;
    const int base = (c & 1) * 64 + lq * 8;
    #pragma unroll
    for (int k2 = 0; k2 < 2; ++k2) {
      af[0][k2] = *(const bf16x8*)(aP[0][seg] + base + k2 * 32);
      af[1][k2] = *(const bf16x8*)(aP[1][seg] + base + k2 * 32);
    }
  };

  bf16x8 aCur[2][2], aNxt[2][2];
  Stg sg;
  loadA(0, aCur);
  stageLoad<256>(Wt, 0, tid, sg);
  stageWrite(Bs[0], tid, sg);
  __syncthreads();
  #pragma unroll
  for (int c = 0; c < 4; ++c) {
    if (c + 1 < 4) { loadA(c + 1, aNxt); stageLoad<256>(Wt, c + 1, tid, sg); }
    chunkMFMA(Bs[c & 1], wc, l15, lq, aCur, acc);
    if (c + 1 < 4) stageWrite(Bs[(c + 1) & 1], tid, sg);
    __syncthreads();
    #pragma unroll
    for (int m = 0; m < 2; ++m)
      #pragma unroll
      for (int k2 = 0; k2 < 2; ++k2) aCur[m][k2] = aNxt[m][k2];
  }

  float bb[4], s1[4], s2[4];
  #pragma unroll
  for (int n = 0; n < 4; ++n) { bb[n] = b[wc * 64 + n * 16 + l15]; s1[n] = 0.f; s2[n] = 0.f; }
  #pragma unroll
  for (int m = 0; m < 2; ++m)
    #pragma unroll
    for (int n = 0; n < 4; ++n) {
      const int col = wc * 64 + n * 16 + l15;
      #pragma unroll
      for (int r = 0; r < 4; ++r) {
        const int row = row0 + wr * 32 + m * 16 + lq * 4 + r;
        if (row < NND) {
          const float o = acc[m][n][r] + bb[n];
          s1[n] += o; s2[n] += o * o;
          h1[(size_t)row * L + col] = f2bf(o);
        }
      }
    }
  #pragma unroll
  for (int n = 0; n < 4; ++n) {
    const int col = wc * 64 + n * 16 + l15;
    atomAddF(&red[col], s1[n]);
    atomAddF(&red[128 + col], s2[n]);
  }
  __syncthreads();
  const int slot = (bid & 63) * L;
  if (tid < 128) atomAddF(&gS[slot + tid], red[tid]);
  else atomAddF(&gS[64 * L + slot + (tid - 128)], red[tid]);
}

// ================= node layer 2: x = relu(relu(BN(h1n)) @ nW2 + nb2) + resid ; fp32 + bf16 shadow =================
__global__ __launch_bounds__(256) void k_node_l2(
    const u16* __restrict__ h1, const float* __restrict__ ss,
    const u16* __restrict__ Wt, const float* __restrict__ b,
    const float* __restrict__ resid, float* __restrict__ x_out,
    u16* __restrict__ x16)
{
  __shared__ char Bs[2][16384];
  const int tid = threadIdx.x, bid = blockIdx.x, row0 = bid * 64;
  const int lane = tid & 63, wid = tid >> 6, wr = wid >> 1, wc = wid & 1;
  const int l15 = lane & 15, lq = lane >> 4;
  const int r0 = row0 + wr * 32 + l15, r1 = r0 + 16;
  const int rr0 = min(r0, NND - 1), rr1 = min(r1, NND - 1);
  const u16* a0 = h1 + (size_t)rr0 * L + lq * 8;
  const u16* a1 = h1 + (size_t)rr1 * L + lq * 8;

  f32x4 acc[2][4];
  #pragma unroll
  for (int m = 0; m < 2; ++m)
    #pragma unroll
    for (int n = 0; n < 4; ++n) acc[m][n] = (f32x4){0.f, 0.f, 0.f, 0.f};

  Stg sg0, sg1;
  stageLoad<128>(Wt, 0, tid, sg0);
  stageLoad<128>(Wt, 1, tid, sg1);
  bf16x8 raw[2][2][2];
  #pragma unroll
  for (int c = 0; c < 2; ++c)
    #pragma unroll
    for (int k2 = 0; k2 < 2; ++k2) {
      raw[c][0][k2] = *(const bf16x8*)(a0 + c * 64 + k2 * 32);
      raw[c][1][k2] = *(const bf16x8*)(a1 + c * 64 + k2 * 32);
    }
  stageWrite(Bs[0], tid, sg0);
  stageWrite(Bs[1], tid, sg1);
  __syncthreads();

  #pragma unroll
  for (int c = 0; c < 2; ++c) {
    bf16x8 af[2][2];
    #pragma unroll
    for (int k2 = 0; k2 < 2; ++k2) {
      const int kg = c * 64 + k2 * 32 + lq * 8;
      const float4 sca = *(const float4*)(ss + kg), scb = *(const float4*)(ss + kg + 4);
      const float4 sha = *(const float4*)(ss + 128 + kg), shb = *(const float4*)(ss + 128 + kg + 4);
      af[0][k2] = bnrelu8(raw[c][0][k2], sca, scb, sha, shb);
      af[1][k2] = bnrelu8(raw[c][1][k2], sca, scb, sha, shb);
    }
    chunkMFMA(Bs[c], wc, l15, lq, af, acc);
  }

  float bb[4];
  #pragma unroll
  for (int n = 0; n < 4; ++n) bb[n] = b[wc * 64 + n * 16 + l15];
  #pragma unroll
  for (int m = 0; m < 2; ++m)
    #pragma unroll
    for (int n = 0; n < 4; ++n) {
      const int col = wc * 64 + n * 16 + l15;
      #pragma unroll
      for (int r = 0; r < 4; ++r) {
        const int row = row0 + wr * 32 + m * 16 + lq * 4 + r;
        if (row < NND) {
          const float o = fmaxf(acc[m][n][r] + bb[n], 0.f) + resid[(size_t)row * L + col];
          x_out[(size_t)row * L + col] = o;
          x16[(size_t)row * L + col] = f2bf(o);
        }
      }
    }
}

extern "C" void kernel_launch(void* const* d_in, const int* in_sizes, int n_in,
                              void* d_out, int out_size, void* d_ws, size_t ws_size,
                              hipStream_t stream) {
  (void)in_sizes; (void)n_in; (void)out_size; (void)ws_size;
  const float* in_x  = (const float*)d_in[0];
  const float* in_ea = (const float*)d_in[1];
  const int*   ei    = (const int*)d_in[2];
  const float* eW1 = (const float*)d_in[3];
  const float* eb1 = (const float*)d_in[4];
  const float* eg1 = (const float*)d_in[5];
  const float* ebe1= (const float*)d_in[6];
  const float* eW2 = (const float*)d_in[7];
  const float* eb2 = (const float*)d_in[8];
  const float* nW1 = (const float*)d_in[9];
  const float* nb1 = (const float*)d_in[10];
  const float* ng1 = (const float*)d_in[11];
  const float* nbe1= (const float*)d_in[12];
  const float* nW2 = (const float*)d_in[13];
  const float* nb2 = (const float*)d_in[14];

  float* x  = (float*)d_out;                    // [NND][L]
  float* ea = (float*)d_out + (size_t)NND * L;  // [E_N][L]

  char* w = (char*)d_ws;
  u16* h1e  = (u16*)w;   w += (size_t)E_N * L * sizeof(u16);   // 153.6 MB
  u16* ea16 = (u16*)w;   w += (size_t)E_N * L * sizeof(u16);   // 153.6 MB
  u16* h1n  = (u16*)w;   w += (size_t)NND * L * sizeof(u16);   // 12.8 MB
  u16* x16  = (u16*)w;   w += (size_t)NND * L * sizeof(u16);   // 12.8 MB
  u16* agg16= (u16*)w;   w += (size_t)NND * L * sizeof(u16);   // 12.8 MB
  float* gS  = (float*)w; w += (size_t)2 * 64 * L * sizeof(float);
  float* ss  = (float*)w; w += 4096;
  u16* eW1t = (u16*)w;   w += (size_t)4 * 128 * 384 * sizeof(u16);
  u16* eW2t = (u16*)w;   w += (size_t)4 * 128 * 128 * sizeof(u16);
  u16* nW1t = (u16*)w;   w += (size_t)4 * 128 * 256 * sizeof(u16);
  u16* nW2t = (u16*)w;   w += (size_t)4 * 128 * 128 * sizeof(u16);
  int* cnt    = (int*)w; w += (size_t)NND * sizeof(int);
  int* cur    = (int*)w; w += (size_t)NND * sizeof(int);
  int* startA = (int*)w; w += (size_t)(NND + 1) * sizeof(int);
  int* eids   = (int*)w; w += (size_t)E_N * sizeof(int);

  const int* srcI = ei;        // edge_index[0]
  const int* dstI = ei + E_N;  // edge_index[1]

  // ---- per-launch pre-pass: x bf16 shadow + weight transpose + CSR build ----
  k_cvt4<<<(NND * L / 4 + 255) / 256, 256, 0, stream>>>(in_x, x16, NND * L / 4);
  k_wt<<<(4 * 384 * 128 + 255) / 256, 256, 0, stream>>>(eW1, eW1t, 384);
  k_wt<<<(4 * 128 * 128 + 255) / 256, 256, 0, stream>>>(eW2, eW2t, 128);
  k_wt<<<(4 * 256 * 128 + 255) / 256, 256, 0, stream>>>(nW1, nW1t, 256);
  k_wt<<<(4 * 128 * 128 + 255) / 256, 256, 0, stream>>>(nW2, nW2t, 128);
  hipMemsetAsync(cnt, 0, (size_t)NND * sizeof(int), stream);
  hipMemsetAsync(cur, 0, (size_t)NND * sizeof(int), stream);
  k_hist<<<(E_N + 255) / 256, 256, 0, stream>>>(dstI, cnt);
  k_scan<<<1, 1024, 0, stream>>>(cnt, startA);
  k_fill<<<(E_N + 255) / 256, 256, 0, stream>>>(dstI, startA, cur, eids);

  const int egrid = E_N / 64;            // 9375
  const int ngrid = (NND + 63) / 64;     // 782

  for (int s = 0; s < 4; ++s) {
    hipMemsetAsync(gS, 0, (size_t)2 * 64 * L * sizeof(float), stream);
    if (s == 0)
      k_edge_l1<true><<<egrid, 256, 0, stream>>>(x16, in_ea, nullptr, srcI, dstI,
          eW1t + (size_t)s * 128 * 384, eb1 + (size_t)s * L, h1e, gS);
    else
      k_edge_l1<false><<<egrid, 256, 0, stream>>>(x16, nullptr, ea16, srcI, dstI,
          eW1t + (size_t)s * 128 * 384, eb1 + (size_t)s * L, h1e, gS);
    k_bnfin<<<1, 128, 0, stream>>>(gS, eg1 + (size_t)s * L, ebe1 + (size_t)s * L,
        1.f / (float)E_N, ss);
    if (s == 0)
      k_edge_l2<true, false><<<egrid, 256, 0, stream>>>(h1e, ss,
          eW2t + (size_t)s * 128 * 128, eb2 + (size_t)s * L, in_ea, nullptr, ea, ea16);
    else if (s < 3)
      k_edge_l2<false, false><<<egrid, 256, 0, stream>>>(h1e, ss,
          eW2t + (size_t)s * 128 * 128, eb2 + (size_t)s * L, nullptr, ea16, ea, ea16);
    else
      k_edge_l2<false, true><<<egrid, 256, 0, stream>>>(h1e, ss,
          eW2t + (size_t)s * 128 * 128, eb2 + (size_t)s * L, nullptr, ea16, ea, ea16);
    k_agg<<<(NND + 3) / 4, 256, 0, stream>>>(ea16, startA, eids, agg16);
    hipMemsetAsync(gS, 0, (size_t)2 * 64 * L * sizeof(float), stream);
    k_node_l1<<<ngrid, 256, 0, stream>>>(x16, agg16,
        nW1t + (size_t)s * 128 * 256, nb1 + (size_t)s * L, h1n, gS);
    k_bnfin<<<1, 128, 0, stream>>>(gS, ng1 + (size_t)s * L, nbe1 + (size_t)s * L,
        1.f / (float)NND, ss);
    k_node_l2<<<ngrid, 256, 0, stream>>>(h1n, ss,
        nW2t + (size_t)s * 128 * 128, nb2 + (size_t)s * L,
        (s == 0) ? in_x : x, x, x16);
  }
}

// Round 5
// 2264.348 us; speedup vs baseline: 1.4203x; 1.0159x over previous
//
#include <hip/hip_runtime.h>
#include <hip/hip_bf16.h>
#include <cstdint>
#include <cstddef>

#define E_N 600000
#define NND 50000
#define L 128

typedef unsigned short u16;
typedef unsigned int u32;
typedef __attribute__((ext_vector_type(8))) short bf16x8;
typedef __attribute__((ext_vector_type(4))) float f32x4;

static __device__ __forceinline__ u16 f2bf(float f) {
  union { float f; u32 u; } c; c.f = f;
  return (u16)((c.u + 0x7fffu + ((c.u >> 16) & 1u)) >> 16);
}
static __device__ __forceinline__ u32 pk2(float a, float b) {
  return (u32)f2bf(a) | ((u32)f2bf(b) << 16);
}
static __device__ __forceinline__ float bf2f(u32 h) {
  union { u32 u; float f; } c; c.u = (h & 0xffffu) << 16; return c.f;
}
static __device__ __forceinline__ void atomAddF(float* p, float v) {
#if defined(__HIP_DEVICE_COMPILE__)
  unsafeAtomicAdd(p, v);
#else
  atomicAdd(p, v);
#endif
}
static __device__ __forceinline__ bf16x8 pack8(float4 a, float4 b) {
  union { bf16x8 v; u32 w[4]; } r;
  r.w[0] = pk2(a.x, a.y); r.w[1] = pk2(a.z, a.w);
  r.w[2] = pk2(b.x, b.y); r.w[3] = pk2(b.z, b.w);
  return r.v;
}
// BN(scale,shift)+ReLU on 8 packed bf16, repack to bf16x8
static __device__ __forceinline__ bf16x8 bnrelu8(bf16x8 raw, float4 sca, float4 scb,
                                                 float4 sha, float4 shb) {
  union { bf16x8 v; u16 h[8]; } in; in.v = raw;
  const float sc[8] = {sca.x, sca.y, sca.z, sca.w, scb.x, scb.y, scb.z, scb.w};
  const float sh[8] = {sha.x, sha.y, sha.z, sha.w, shb.x, shb.y, shb.z, shb.w};
  float f[8];
  #pragma unroll
  for (int i = 0; i < 8; ++i) f[i] = fmaxf(bf2f(in.h[i]) * sc[i] + sh[i], 0.f);
  union { bf16x8 v; u32 w[4]; } r;
  #pragma unroll
  for (int i = 0; i < 4; ++i) r.w[i] = pk2(f[2 * i], f[2 * i + 1]);
  return r.v;
}

#define MFMA(a, bfr, c) __builtin_amdgcn_mfma_f32_16x16x32_bf16((a), (bfr), (c), 0, 0, 0)

// ---- B-chunk staging: Wt rows n=0..127, k-window [kc*64, kc*64+64), 16 KB, XOR-swizzled ----
struct Stg { uint4 v[4]; };
template <int KF>
static __device__ __forceinline__ void stageLoad(const u16* __restrict__ Wt, int kc, int tid, Stg& s) {
  #pragma unroll
  for (int i = 0; i < 4; ++i) {
    const int slot = tid + i * 256;
    const int n = slot >> 3, kq = slot & 7;
    s.v[i] = *(const uint4*)(Wt + (size_t)n * KF + kc * 64 + kq * 8);
  }
}
static __device__ __forceinline__ void stageWrite(char* BsB, int tid, const Stg& s) {
  #pragma unroll
  for (int i = 0; i < 4; ++i) {
    const int slot = tid + i * 256;
    const int n = slot >> 3, kq = slot & 7;
    *(uint4*)(BsB + ((n * 128 + kq * 16) ^ ((n & 7) << 4))) = s.v[i];
  }
}
// ---- one 64-k chunk of MFMA: A frags in regs, B frags from swizzled LDS ----
static __device__ __forceinline__ void chunkMFMA(const char* BsB, int wc, int l15, int lq,
                                                 const bf16x8 (&af)[2][2], f32x4 (&acc)[2][4]) {
  #pragma unroll
  for (int k2 = 0; k2 < 2; ++k2) {
    #pragma unroll
    for (int n = 0; n < 4; ++n) {
      const int col = wc * 64 + n * 16 + l15;
      const bf16x8 bfr = *(const bf16x8*)(BsB + ((col * 128 + k2 * 64 + lq * 16) ^ ((col & 7) << 4)));
      acc[0][n] = MFMA(af[0][k2], bfr, acc[0][n]);
      acc[1][n] = MFMA(af[1][k2], bfr, acc[1][n]);
    }
  }
}

// ================= prepass: fp32 -> bf16 convert (4-wide) =================
__global__ __launch_bounds__(256) void k_cvt4(const float* __restrict__ in,
                                              u16* __restrict__ out, int n4) {
  const int i = blockIdx.x * 256 + threadIdx.x;
  if (i < n4) {
    const float4 v = *(const float4*)(in + (size_t)i * 4);
    uint2 o; o.x = pk2(v.x, v.y); o.y = pk2(v.z, v.w);
    *(uint2*)(out + (size_t)i * 4) = o;
  }
}

// ================= weight pre-transpose: W[4][K][128] -> Wt[4][128][K] bf16 =================
__global__ void k_wt(const float* __restrict__ W, u16* __restrict__ Wt, int K) {
  const int idx = blockIdx.x * 256 + threadIdx.x;
  const int total = 4 * K * 128;
  if (idx >= total) return;
  const int s = idx / (K * 128);
  const int rem = idx - s * K * 128;
  const int n = rem / K;
  const int k = rem - n * K;
  Wt[idx] = f2bf(W[(size_t)s * K * 128 + (size_t)k * 128 + n]);
}

// ================= CSR build =================
__global__ void k_hist(const int* __restrict__ dstI, int* __restrict__ cnt) {
  const int i = blockIdx.x * 256 + threadIdx.x;
  if (i < E_N) atomicAdd(&cnt[dstI[i]], 1);
}

__global__ __launch_bounds__(1024) void k_scan(const int* __restrict__ cnt, int* __restrict__ startA) {
  __shared__ int buf[1024];
  __shared__ int carry;
  const int tid = threadIdx.x;
  if (tid == 0) carry = 0;
  __syncthreads();
  for (int base = 0; base < NND; base += 1024) {
    int v = (base + tid < NND) ? cnt[base + tid] : 0;
    buf[tid] = v;
    __syncthreads();
    for (int off = 1; off < 1024; off <<= 1) {
      int t = (tid >= off) ? buf[tid - off] : 0;
      __syncthreads();
      buf[tid] += t;
      __syncthreads();
    }
    const int incl = buf[tid];
    const int c = carry;
    if (base + tid < NND) startA[base + tid] = c + incl - v;
    __syncthreads();
    if (tid == 1023) carry = c + incl;
    __syncthreads();
  }
  if (tid == 0) startA[NND] = carry;
}

__global__ void k_fill(const int* __restrict__ dstI, const int* __restrict__ startA,
                       int* __restrict__ cur, int* __restrict__ eids) {
  const int i = blockIdx.x * 256 + threadIdx.x;
  if (i < E_N) {
    const int d = dstI[i];
    const int pos = atomicAdd(&cur[d], 1);
    eids[startA[d] + pos] = i;
  }
}

// permuted index arrays: srcP[i] = srcI[perm[i]], dstP[i] = dstI[perm[i]]
__global__ void k_perm(const int* __restrict__ srcI, const int* __restrict__ dstI,
                       const int* __restrict__ perm,
                       int* __restrict__ srcP, int* __restrict__ dstP) {
  const int i = blockIdx.x * 256 + threadIdx.x;
  if (i < E_N) {
    const int e = perm[i];
    srcP[i] = srcI[e];
    dstP[i] = dstI[e];
  }
}

// ================= aggregation: agg16[n] = bf16( sum of contiguous permuted ea16 rows ) =================
__global__ __launch_bounds__(256) void k_agg(const u16* __restrict__ ea16,
                                             const int* __restrict__ startA,
                                             u16* __restrict__ agg16) {
  const int node = blockIdx.x * 4 + (threadIdx.x >> 6);
  const int lane = threadIdx.x & 63;
  if (node >= NND) return;
  const int s = startA[node], e = startA[node + 1];
  float a0 = 0.f, a1 = 0.f, b0 = 0.f, b1 = 0.f;
  int i = s;
  for (; i + 1 < e; i += 2) {
    const u32 v0 = *(const u32*)(ea16 + (size_t)i * L + lane * 2);
    const u32 v1 = *(const u32*)(ea16 + (size_t)(i + 1) * L + lane * 2);
    a0 += bf2f(v0); a1 += bf2f(v0 >> 16);
    b0 += bf2f(v1); b1 += bf2f(v1 >> 16);
  }
  if (i < e) {
    const u32 v = *(const u32*)(ea16 + (size_t)i * L + lane * 2);
    a0 += bf2f(v); a1 += bf2f(v >> 16);
  }
  *(u32*)(agg16 + (size_t)node * L + lane * 2) = pk2(a0 + b0, a1 + b1);
}

// ================= BN finalize =================
__global__ void k_bnfin(const float* __restrict__ gS, const float* __restrict__ g,
                        const float* __restrict__ be, float invM, float* __restrict__ ss) {
  const int c = threadIdx.x;
  float s1 = 0.f, s2 = 0.f;
  for (int j = 0; j < 64; ++j) { s1 += gS[j * L + c]; s2 += gS[64 * L + j * L + c]; }
  const float mean = s1 * invM;
  const float var = s2 * invM - mean * mean;
  const float sc = g[c] * rsqrtf(var + 1e-5f);
  ss[c] = sc;
  ss[L + c] = be[c] - mean * sc;
}

// ================= edge layer 1 (permuted rows): h1[i] = concat(x[dstP],x[srcP],ea[i]) @ W1 + b1 ; BN stats =================
// chunk order: ea0, ea1, dst0, dst1, src0, src1  (B k-windows: 4,5,0,1,2,3)
template <bool EA32>
__global__ __launch_bounds__(256) void k_edge_l1(
    const u16* __restrict__ x16, const float* __restrict__ ea32,
    const u16* __restrict__ ea16, const int* __restrict__ perm,
    const int* __restrict__ srcP, const int* __restrict__ dstP,
    const u16* __restrict__ Wt, const float* __restrict__ b,
    u16* __restrict__ h1, float* __restrict__ gS)
{
  __shared__ char Bs[2][16384];
  __shared__ float red[256];
  const int tid = threadIdx.x, bid = blockIdx.x, row0 = bid * 64;
  red[tid] = 0.f;
  const int lane = tid & 63, wid = tid >> 6, wr = wid >> 1, wc = wid & 1;
  const int l15 = lane & 15, lq = lane >> 4;
  const int r0 = row0 + wr * 32 + l15, r1 = r0 + 16;
  const int d0 = dstP[r0], d1 = dstP[r1];
  const int s0 = srcP[r0], s1v = srcP[r1];

  const u16* dp0 = x16 + (size_t)d0 * L;
  const u16* dp1 = x16 + (size_t)d1 * L;
  const u16* sp0 = x16 + (size_t)s0 * L;
  const u16* sp1 = x16 + (size_t)s1v * L;

  // ---- preload ea (streaming HBM) and src (random gather) fully ----
  bf16x8 aEa[2][2][2], aSrc[2][2][2]; // [chunk][m][k2]
  if (EA32) {
    const float* pE0 = ea32 + (size_t)perm[r0] * L;
    const float* pE1 = ea32 + (size_t)perm[r1] * L;
    #pragma unroll
    for (int c = 0; c < 2; ++c)
      #pragma unroll
      for (int k2 = 0; k2 < 2; ++k2) {
        const int off = c * 64 + k2 * 32 + lq * 8;
        aEa[c][0][k2] = pack8(*(const float4*)(pE0 + off), *(const float4*)(pE0 + off + 4));
        aEa[c][1][k2] = pack8(*(const float4*)(pE1 + off), *(const float4*)(pE1 + off + 4));
      }
  } else {
    const u16* pE0 = ea16 + (size_t)r0 * L;
    const u16* pE1 = ea16 + (size_t)r1 * L;
    #pragma unroll
    for (int c = 0; c < 2; ++c)
      #pragma unroll
      for (int k2 = 0; k2 < 2; ++k2) {
        const int off = c * 64 + k2 * 32 + lq * 8;
        aEa[c][0][k2] = *(const bf16x8*)(pE0 + off);
        aEa[c][1][k2] = *(const bf16x8*)(pE1 + off);
      }
  }
  #pragma unroll
  for (int c = 0; c < 2; ++c)
    #pragma unroll
    for (int k2 = 0; k2 < 2; ++k2) {
      const int off = c * 64 + k2 * 32 + lq * 8;
      aSrc[c][0][k2] = *(const bf16x8*)(sp0 + off);
      aSrc[c][1][k2] = *(const bf16x8*)(sp1 + off);
    }

  f32x4 acc[2][4];
  #pragma unroll
  for (int m = 0; m < 2; ++m)
    #pragma unroll
    for (int n = 0; n < 4; ++n) acc[m][n] = (f32x4){0.f, 0.f, 0.f, 0.f};

  const int kcMap[6] = {4, 5, 0, 1, 2, 3};
  Stg sg;
  stageLoad<384>(Wt, kcMap[0], tid, sg);
  stageWrite(Bs[0], tid, sg);
  __syncthreads();
  #pragma unroll
  for (int cc = 0; cc < 6; ++cc) {
    if (cc < 5) stageLoad<384>(Wt, kcMap[cc + 1], tid, sg);
    bf16x8 af[2][2];
    if (cc < 2) {
      #pragma unroll
      for (int m = 0; m < 2; ++m)
        #pragma unroll
        for (int k2 = 0; k2 < 2; ++k2) af[m][k2] = aEa[cc][m][k2];
    } else if (cc < 4) {
      const int c = cc - 2;
      #pragma unroll
      for (int k2 = 0; k2 < 2; ++k2) {
        const int off = c * 64 + k2 * 32 + lq * 8;
        af[0][k2] = *(const bf16x8*)(dp0 + off);
        af[1][k2] = *(const bf16x8*)(dp1 + off);
      }
    } else {
      #pragma unroll
      for (int m = 0; m < 2; ++m)
        #pragma unroll
        for (int k2 = 0; k2 < 2; ++k2) af[m][k2] = aSrc[cc - 4][m][k2];
    }
    chunkMFMA(Bs[cc & 1], wc, l15, lq, af, acc);
    if (cc < 5) stageWrite(Bs[(cc + 1) & 1], tid, sg);
    __syncthreads();
  }

  float bb[4], s1[4], s2[4];
  #pragma unroll
  for (int n = 0; n < 4; ++n) { bb[n] = b[wc * 64 + n * 16 + l15]; s1[n] = 0.f; s2[n] = 0.f; }
  #pragma unroll
  for (int m = 0; m < 2; ++m)
    #pragma unroll
    for (int n = 0; n < 4; ++n) {
      const int col = wc * 64 + n * 16 + l15;
      #pragma unroll
      for (int r = 0; r < 4; ++r) {
        const int row = row0 + wr * 32 + m * 16 + lq * 4 + r;
        const float o = acc[m][n][r] + bb[n];
        s1[n] += o; s2[n] += o * o;
        h1[(size_t)row * L + col] = f2bf(o);
      }
    }
  #pragma unroll
  for (int n = 0; n < 4; ++n) {
    const int col = wc * 64 + n * 16 + l15;
    atomAddF(&red[col], s1[n]);
    atomAddF(&red[128 + col], s2[n]);
  }
  __syncthreads();
  const int slot = (bid & 63) * L;
  if (tid < 128) atomAddF(&gS[slot + tid], red[tid]);
  else atomAddF(&gS[64 * L + slot + (tid - 128)], red[tid]);
}

// ================= edge layer 2 (permuted rows): ea16[i] = bf16( relu(relu(BN(h1)) @ W2 + b2) + resid ) =================
template <bool EA32, bool WF32>
__global__ __launch_bounds__(256) void k_edge_l2(
    const u16* __restrict__ h1, const float* __restrict__ ss,
    const u16* __restrict__ Wt, const float* __restrict__ b,
    const float* __restrict__ resid32, const u16* __restrict__ resid16,
    const int* __restrict__ perm,
    float* __restrict__ ea_out, u16* __restrict__ ea16)
{
  __shared__ char Bs[2][16384];
  const int tid = threadIdx.x, bid = blockIdx.x, row0 = bid * 64;
  const int lane = tid & 63, wid = tid >> 6, wr = wid >> 1, wc = wid & 1;
  const int l15 = lane & 15, lq = lane >> 4;
  const int r0 = row0 + wr * 32 + l15, r1 = r0 + 16;
  const u16* a0 = h1 + (size_t)r0 * L + lq * 8;
  const u16* a1 = h1 + (size_t)r1 * L + lq * 8;

  f32x4 acc[2][4];
  #pragma unroll
  for (int m = 0; m < 2; ++m)
    #pragma unroll
    for (int n = 0; n < 4; ++n) acc[m][n] = (f32x4){0.f, 0.f, 0.f, 0.f};

  Stg sg0, sg1;
  stageLoad<128>(Wt, 0, tid, sg0);
  stageLoad<128>(Wt, 1, tid, sg1);
  bf16x8 raw[2][2][2]; // [chunk][m][k2]
  #pragma unroll
  for (int c = 0; c < 2; ++c)
    #pragma unroll
    for (int k2 = 0; k2 < 2; ++k2) {
      raw[c][0][k2] = *(const bf16x8*)(a0 + c * 64 + k2 * 32);
      raw[c][1][k2] = *(const bf16x8*)(a1 + c * 64 + k2 * 32);
    }
  stageWrite(Bs[0], tid, sg0);
  stageWrite(Bs[1], tid, sg1);
  __syncthreads();

  #pragma unroll
  for (int c = 0; c < 2; ++c) {
    bf16x8 af[2][2];
    #pragma unroll
    for (int k2 = 0; k2 < 2; ++k2) {
      const int kg = c * 64 + k2 * 32 + lq * 8;
      const float4 sca = *(const float4*)(ss + kg), scb = *(const float4*)(ss + kg + 4);
      const float4 sha = *(const float4*)(ss + 128 + kg), shb = *(const float4*)(ss + 128 + kg + 4);
      af[0][k2] = bnrelu8(raw[c][0][k2], sca, scb, sha, shb);
      af[1][k2] = bnrelu8(raw[c][1][k2], sca, scb, sha, shb);
    }
    chunkMFMA(Bs[c], wc, l15, lq, af, acc);
  }

  float bb[4];
  #pragma unroll
  for (int n = 0; n < 4; ++n) bb[n] = b[wc * 64 + n * 16 + l15];
  #pragma unroll
  for (int m = 0; m < 2; ++m)
    #pragma unroll
    for (int n = 0; n < 4; ++n) {
      const int col = wc * 64 + n * 16 + l15;
      #pragma unroll
      for (int r = 0; r < 4; ++r) {
        const int row = row0 + wr * 32 + m * 16 + lq * 4 + r;
        float rs;
        if (EA32) rs = resid32[(size_t)perm[row] * L + col];
        else      rs = bf2f(resid16[(size_t)row * L + col]);
        const float o = fmaxf(acc[m][n][r] + bb[n], 0.f) + rs;
        if (WF32) ea_out[(size_t)perm[row] * L + col] = o;
        ea16[(size_t)row * L + col] = f2bf(o);
      }
    }
}

// ================= node layer 1: h1n = concat(x,agg) @ nW1 + nb1 ; BN stats =================
__global__ __launch_bounds__(256) void k_node_l1(
    const u16* __restrict__ x16, const u16* __restrict__ agg16,
    const u16* __restrict__ Wt, const float* __restrict__ b,
    u16* __restrict__ h1, float* __restrict__ gS)
{
  __shared__ char Bs[2][16384];
  __shared__ float red[256];
  const int tid = threadIdx.x, bid = blockIdx.x, row0 = bid * 64;
  red[tid] = 0.f;
  const int lane = tid & 63, wid = tid >> 6, wr = wid >> 1, wc = wid & 1;
  const int l15 = lane & 15, lq = lane >> 4;
  const int r0 = row0 + wr * 32 + l15, r1 = r0 + 16;
  const int rr0 = min(r0, NND - 1), rr1 = min(r1, NND - 1);

  const u16* aP[2][2];
  aP[0][0] = x16 + (size_t)rr0 * L;  aP[1][0] = x16 + (size_t)rr1 * L;
  aP[0][1] = agg16 + (size_t)rr0 * L; aP[1][1] = agg16 + (size_t)rr1 * L;

  f32x4 acc[2][4];
  #pragma unroll
  for (int m = 0; m < 2; ++m)
    #pragma unroll
    for (int n = 0; n < 4; ++n) acc[m][n] = (f32x4){0.f, 0.f, 0.f, 0.f};

  auto loadA = [&](int c, bf16x8 (&af)[2][2]) {
    const int seg = c >> 1;
    const int base = (c & 1) * 64 + lq * 8;
    #pragma unroll
    for (int k2 = 0; k2 < 2; ++k2) {
      af[0][k2] = *(const bf16x8*)(aP[0][seg] + base + k2 * 32);
      af[1][k2] = *(const bf16x8*)(aP[1][seg] + base + k2 * 32);
    }
  };

  bf16x8 aCur[2][2], aNxt[2][2];
  Stg sg;
  loadA(0, aCur);
  stageLoad<256>(Wt, 0, tid, sg);
  stageWrite(Bs[0], tid, sg);
  __syncthreads();
  #pragma unroll
  for (int c = 0; c < 4; ++c) {
    if (c + 1 < 4) { loadA(c + 1, aNxt); stageLoad<256>(Wt, c + 1, tid, sg); }
    chunkMFMA(Bs[c & 1], wc, l15, lq, aCur, acc);
    if (c + 1 < 4) stageWrite(Bs[(c + 1) & 1], tid, sg);
    __syncthreads();
    #pragma unroll
    for (int m = 0; m < 2; ++m)
      #pragma unroll
      for (int k2 = 0; k2 < 2; ++k2) aCur[m][k2] = aNxt[m][k2];
  }

  float bb[4], s1[4], s2[4];
  #pragma unroll
  for (int n = 0; n < 4; ++n) { bb[n] = b[wc * 64 + n * 16 + l15]; s1[n] = 0.f; s2[n] = 0.f; }
  #pragma unroll
  for (int m = 0; m < 2; ++m)
    #pragma unroll
    for (int n = 0; n < 4; ++n) {
      const int col = wc * 64 + n * 16 + l15;
      #pragma unroll
      for (int r = 0; r < 4; ++r) {
        const int row = row0 + wr * 32 + m * 16 + lq * 4 + r;
        if (row < NND) {
          const float o = acc[m][n][r] + bb[n];
          s1[n] += o; s2[n] += o * o;
          h1[(size_t)row * L + col] = f2bf(o);
        }
      }
    }
  #pragma unroll
  for (int n = 0; n < 4; ++n) {
    const int col = wc * 64 + n * 16 + l15;
    atomAddF(&red[col], s1[n]);
    atomAddF(&red[128 + col], s2[n]);
  }
  __syncthreads();
  const int slot = (bid & 63) * L;
  if (tid < 128) atomAddF(&gS[slot + tid], red[tid]);
  else atomAddF(&gS[64 * L + slot + (tid - 128)], red[tid]);
}

// ================= node layer 2: x = relu(relu(BN(h1n)) @ nW2 + nb2) + resid ; fp32 + bf16 shadow =================
__global__ __launch_bounds__(256) void k_node_l2(
    const u16* __restrict__ h1, const float* __restrict__ ss,
    const u16* __restrict__ Wt, const float* __restrict__ b,
    const float* __restrict__ resid, float* __restrict__ x_out,
    u16* __restrict__ x16)
{
  __shared__ char Bs[2][16384];
  const int tid = threadIdx.x, bid = blockIdx.x, row0 = bid * 64;
  const int lane = tid & 63, wid = tid >> 6, wr = wid >> 1, wc = wid & 1;
  const int l15 = lane & 15, lq = lane >> 4;
  const int r0 = row0 + wr * 32 + l15, r1 = r0 + 16;
  const int rr0 = min(r0, NND - 1), rr1 = min(r1, NND - 1);
  const u16* a0 = h1 + (size_t)rr0 * L + lq * 8;
  const u16* a1 = h1 + (size_t)rr1 * L + lq * 8;

  f32x4 acc[2][4];
  #pragma unroll
  for (int m = 0; m < 2; ++m)
    #pragma unroll
    for (int n = 0; n < 4; ++n) acc[m][n] = (f32x4){0.f, 0.f, 0.f, 0.f};

  Stg sg0, sg1;
  stageLoad<128>(Wt, 0, tid, sg0);
  stageLoad<128>(Wt, 1, tid, sg1);
  bf16x8 raw[2][2][2];
  #pragma unroll
  for (int c = 0; c < 2; ++c)
    #pragma unroll
    for (int k2 = 0; k2 < 2; ++k2) {
      raw[c][0][k2] = *(const bf16x8*)(a0 + c * 64 + k2 * 32);
      raw[c][1][k2] = *(const bf16x8*)(a1 + c * 64 + k2 * 32);
    }
  stageWrite(Bs[0], tid, sg0);
  stageWrite(Bs[1], tid, sg1);
  __syncthreads();

  #pragma unroll
  for (int c = 0; c < 2; ++c) {
    bf16x8 af[2][2];
    #pragma unroll
    for (int k2 = 0; k2 < 2; ++k2) {
      const int kg = c * 64 + k2 * 32 + lq * 8;
      const float4 sca = *(const float4*)(ss + kg), scb = *(const float4*)(ss + kg + 4);
      const float4 sha = *(const float4*)(ss + 128 + kg), shb = *(const float4*)(ss + 128 + kg + 4);
      af[0][k2] = bnrelu8(raw[c][0][k2], sca, scb, sha, shb);
      af[1][k2] = bnrelu8(raw[c][1][k2], sca, scb, sha, shb);
    }
    chunkMFMA(Bs[c], wc, l15, lq, af, acc);
  }

  float bb[4];
  #pragma unroll
  for (int n = 0; n < 4; ++n) bb[n] = b[wc * 64 + n * 16 + l15];
  #pragma unroll
  for (int m = 0; m < 2; ++m)
    #pragma unroll
    for (int n = 0; n < 4; ++n) {
      const int col = wc * 64 + n * 16 + l15;
      #pragma unroll
      for (int r = 0; r < 4; ++r) {
        const int row = row0 + wr * 32 + m * 16 + lq * 4 + r;
        if (row < NND) {
          const float o = fmaxf(acc[m][n][r] + bb[n], 0.f) + resid[(size_t)row * L + col];
          x_out[(size_t)row * L + col] = o;
          x16[(size_t)row * L + col] = f2bf(o);
        }
      }
    }
}

extern "C" void kernel_launch(void* const* d_in, const int* in_sizes, int n_in,
                              void* d_out, int out_size, void* d_ws, size_t ws_size,
                              hipStream_t stream) {
  (void)in_sizes; (void)n_in; (void)out_size; (void)ws_size;
  const float* in_x  = (const float*)d_in[0];
  const float* in_ea = (const float*)d_in[1];
  const int*   ei    = (const int*)d_in[2];
  const float* eW1 = (const float*)d_in[3];
  const float* eb1 = (const float*)d_in[4];
  const float* eg1 = (const float*)d_in[5];
  const float* ebe1= (const float*)d_in[6];
  const float* eW2 = (const float*)d_in[7];
  const float* eb2 = (const float*)d_in[8];
  const float* nW1 = (const float*)d_in[9];
  const float* nb1 = (const float*)d_in[10];
  const float* ng1 = (const float*)d_in[11];
  const float* nbe1= (const float*)d_in[12];
  const float* nW2 = (const float*)d_in[13];
  const float* nb2 = (const float*)d_in[14];

  float* x  = (float*)d_out;                    // [NND][L]
  float* ea = (float*)d_out + (size_t)NND * L;  // [E_N][L]

  char* w = (char*)d_ws;
  u16* h1e  = (u16*)w;   w += (size_t)E_N * L * sizeof(u16);   // 153.6 MB (permuted)
  u16* ea16 = (u16*)w;   w += (size_t)E_N * L * sizeof(u16);   // 153.6 MB (permuted)
  u16* h1n  = (u16*)w;   w += (size_t)NND * L * sizeof(u16);
  u16* x16  = (u16*)w;   w += (size_t)NND * L * sizeof(u16);
  u16* agg16= (u16*)w;   w += (size_t)NND * L * sizeof(u16);
  float* gS  = (float*)w; w += (size_t)2 * 64 * L * sizeof(float);
  float* ss  = (float*)w; w += 4096;
  u16* eW1t = (u16*)w;   w += (size_t)4 * 128 * 384 * sizeof(u16);
  u16* eW2t = (u16*)w;   w += (size_t)4 * 128 * 128 * sizeof(u16);
  u16* nW1t = (u16*)w;   w += (size_t)4 * 128 * 256 * sizeof(u16);
  u16* nW2t = (u16*)w;   w += (size_t)4 * 128 * 128 * sizeof(u16);
  int* cnt    = (int*)w; w += (size_t)NND * sizeof(int);
  int* cur    = (int*)w; w += (size_t)NND * sizeof(int);
  int* startA = (int*)w; w += (size_t)(NND + 64) * sizeof(int);
  int* eids   = (int*)w; w += (size_t)E_N * sizeof(int);     // = perm
  int* srcP   = (int*)w; w += (size_t)E_N * sizeof(int);
  int* dstP   = (int*)w; w += (size_t)E_N * sizeof(int);

  const int* srcI = ei;        // edge_index[0]
  const int* dstI = ei + E_N;  // edge_index[1]

  // ---- per-launch pre-pass: bf16 shadows + weight transpose + CSR build + permuted indices ----
  k_cvt4<<<(NND * L / 4 + 255) / 256, 256, 0, stream>>>(in_x, x16, NND * L / 4);
  k_wt<<<(4 * 384 * 128 + 255) / 256, 256, 0, stream>>>(eW1, eW1t, 384);
  k_wt<<<(4 * 128 * 128 + 255) / 256, 256, 0, stream>>>(eW2, eW2t, 128);
  k_wt<<<(4 * 256 * 128 + 255) / 256, 256, 0, stream>>>(nW1, nW1t, 256);
  k_wt<<<(4 * 128 * 128 + 255) / 256, 256, 0, stream>>>(nW2, nW2t, 128);
  hipMemsetAsync(cnt, 0, (size_t)NND * sizeof(int), stream);
  hipMemsetAsync(cur, 0, (size_t)NND * sizeof(int), stream);
  k_hist<<<(E_N + 255) / 256, 256, 0, stream>>>(dstI, cnt);
  k_scan<<<1, 1024, 0, stream>>>(cnt, startA);
  k_fill<<<(E_N + 255) / 256, 256, 0, stream>>>(dstI, startA, cur, eids);
  k_perm<<<(E_N + 255) / 256, 256, 0, stream>>>(srcI, dstI, eids, srcP, dstP);

  const int egrid = E_N / 64;            // 9375
  const int ngrid = (NND + 63) / 64;     // 782

  for (int s = 0; s < 4; ++s) {
    hipMemsetAsync(gS, 0, (size_t)2 * 64 * L * sizeof(float), stream);
    if (s == 0)
      k_edge_l1<true><<<egrid, 256, 0, stream>>>(x16, in_ea, nullptr, eids, srcP, dstP,
          eW1t + (size_t)s * 128 * 384, eb1 + (size_t)s * L, h1e, gS);
    else
      k_edge_l1<false><<<egrid, 256, 0, stream>>>(x16, nullptr, ea16, eids, srcP, dstP,
          eW1t + (size_t)s * 128 * 384, eb1 + (size_t)s * L, h1e, gS);
    k_bnfin<<<1, 128, 0, stream>>>(gS, eg1 + (size_t)s * L, ebe1 + (size_t)s * L,
        1.f / (float)E_N, ss);
    if (s == 0)
      k_edge_l2<true, false><<<egrid, 256, 0, stream>>>(h1e, ss,
          eW2t + (size_t)s * 128 * 128, eb2 + (size_t)s * L, in_ea, nullptr, eids, ea, ea16);
    else if (s < 3)
      k_edge_l2<false, false><<<egrid, 256, 0, stream>>>(h1e, ss,
          eW2t + (size_t)s * 128 * 128, eb2 + (size_t)s * L, nullptr, ea16, eids, ea, ea16);
    else
      k_edge_l2<false, true><<<egrid, 256, 0, stream>>>(h1e, ss,
          eW2t + (size_t)s * 128 * 128, eb2 + (size_t)s * L, nullptr, ea16, eids, ea, ea16);
    k_agg<<<(NND + 3) / 4, 256, 0, stream>>>(ea16, startA, agg16);
    hipMemsetAsync(gS, 0, (size_t)2 * 64 * L * sizeof(float), stream);
    k_node_l1<<<ngrid, 256, 0, stream>>>(x16, agg16,
        nW1t + (size_t)s * 128 * 256, nb1 + (size_t)s * L, h1n, gS);
    k_bnfin<<<1, 128, 0, stream>>>(gS, ng1 + (size_t)s * L, nbe1 + (size_t)s * L,
        1.f / (float)NND, ss);
    k_node_l2<<<ngrid, 256, 0, stream>>>(h1n, ss,
        nW2t + (size_t)s * 128 * 128, nb2 + (size_t)s * L,
        (s == 0) ? in_x : x, x, x16);
  }
}